// Round 12
// baseline (695.762 us; speedup 1.0000x reference)
//
#include <hip/hip_runtime.h>
#include <cstdint>

// ---------- types / helpers ----------
typedef __attribute__((ext_vector_type(8))) short short8;
typedef __attribute__((ext_vector_type(4))) float f32x4;
typedef __attribute__((ext_vector_type(2))) float f32x2;
typedef __attribute__((ext_vector_type(4))) int i32x4;
typedef unsigned short us16;
typedef unsigned char u8;

#define DEV __device__ __forceinline__

DEV u8 f2fp8(float f){      // OCP e4m3fn via HW cvt (RNE, saturating)
  int p = __builtin_amdgcn_cvt_pk_fp8_f32(f, f, 0, false);
  return (u8)(p & 0xFF);
}
template<int SEL> DEV float fp8tof(int dw){
#if __has_builtin(__builtin_amdgcn_cvt_f32_fp8)
  return __builtin_amdgcn_cvt_f32_fp8(dw, SEL);
#else
  int b = (dw >> (8*SEL)) & 255;
  int e = (b>>3)&15, m = b&7;
  float v;
  if (e){ union{unsigned u; float f;} x; x.u = (unsigned)(((e+120)<<23) | (m<<20)); v = x.f; }
  else v = (float)m * 0.001953125f;
  return (b & 128) ? -v : v;
#endif
}
DEV f32x4 dq8x4(int dw){
#if __has_builtin(__builtin_amdgcn_cvt_pk_f32_fp8)
  f32x2 lo = __builtin_amdgcn_cvt_pk_f32_fp8(dw, false);
  f32x2 hi = __builtin_amdgcn_cvt_pk_f32_fp8(dw, true);
  return (f32x4){lo.x, lo.y, hi.x, hi.y};
#else
  return (f32x4){fp8tof<0>(dw), fp8tof<1>(dw), fp8tof<2>(dw), fp8tof<3>(dw)};
#endif
}
DEV float fsig(float x){
  float e = __builtin_amdgcn_exp2f(-1.4426950408889634f * x);
  return __builtin_amdgcn_rcpf(1.0f + e);
}
DEV float ftanh(float x){
  float e = __builtin_amdgcn_exp2f(-2.8853900817779268f * x);
  return fmaf(2.0f, __builtin_amdgcn_rcpf(1.0f + e), -1.0f);
}
DEV float fsoftplus(float x){
  float ax = fabsf(x);
  float e = __builtin_amdgcn_exp2f(-1.4426950408889634f * ax);
  float l = 0.69314718055994531f * __builtin_amdgcn_logf(1.0f + e);
  return fmaxf(x, 0.0f) + l;
}
DEV f32x4 mfma16f8(long a, long b, f32x4 c){
  return __builtin_amdgcn_mfma_f32_16x16x32_fp8_fp8(a, b, c, 0, 0, 0);
}
DEV unsigned pk4fp8(float a, float b, float c, float d){
  unsigned lo = (unsigned)__builtin_amdgcn_cvt_pk_fp8_f32(a, b, 0, false) & 0xFFFFu;
  unsigned hi = (unsigned)__builtin_amdgcn_cvt_pk_fp8_f32(c, d, 0, false) & 0xFFFFu;
  return lo | (hi << 16);
}

// Raw LDS barrier: drains LDS ops only; global loads/stores float across.
DEV void lds_barrier(){
  asm volatile("s_waitcnt lgkmcnt(0)" ::: "memory");
  __builtin_amdgcn_s_barrier();
  asm volatile("" ::: "memory");
}

// Dims: B=256, T=WN=200, HH=256/dir, gates=1024, tags K=12.
// MFMA 16x16x32 fragments: A: lane L holds A[m=L&15][k=(L>>4)*8+j];
// B: lane L holds B[k=(L>>4)*8+j][n=L&15]; D: lane L reg r = D[(L>>4)*4+r][L&15].
// k_lstm: 4 batch rows per block, row j in A-slot 4j (1-row epilogue/thread).
// k_g12/k_tail: R5 chunked structure widened to 512 threads (per-wave work
// halved, same LDS) -> 2x waves/CU for latency hiding (R5's k_lstm lever).

// ---------- merged preprocessing bodies ----------

// LSTM Whh B-frag swizzle (16-wave layout): [w(16)][gt(4)][kc(8)][lane x 8B]
DEV void swz_lstm16_one(int tid, const float* __restrict__ W, u8* __restrict__ dst){
  int e = tid & 511, chunk = tid >> 9;       // chunk = w*32 + gt*8 + kc
  int L = e >> 3, j = e & 7;
  int kc = chunk & 7, gt = (chunk >> 3) & 3, w = chunk >> 5;
  int g = gt * 256 + w * 16 + (L & 15);
  int k = kc * 32 + (L >> 4) * 8 + j;
  dst[tid] = f2fp8(W[g * 256 + k]);
}

// char gate table: ctab[dir][v][gcol(256)][gt(4)] fp8 = fp8(emb[v]@Wih^T + b)
DEV void ctab_one(int vd, int gcol, const float* __restrict__ emb,
                  const float* __restrict__ Wih, const float* __restrict__ bb,
                  u8* __restrict__ ctab){
  int v = vd & 127, dir = vd >> 7;
  float val[4];
  #pragma unroll
  for (int gt = 0; gt < 4; ++gt){
    int g = gt * 256 + gcol;
    float s = bb[g];
    for (int k = 0; k < 30; ++k) s += emb[v * 30 + k] * Wih[g * 30 + k];
    val[gt] = s;
  }
  unsigned pk = pk4fp8(val[0], val[1], val[2], val[3]);
  *(unsigned*)&ctab[((dir * 128 + v) * 256 + gcol) * 4] = pk;
}

// Wih (word) B-frag swizzle: [ntile(64)][kc(4)][lane x 8B]
DEV void swz_gin_one(int tid, const float* __restrict__ W, u8* __restrict__ dst){
  int e = tid & 511, chunk = tid >> 9;
  int L = e >> 3, j = e & 7;
  int kc = chunk & 3, ntile = chunk >> 2;
  int g = ntile * 16 + (L & 15);
  int k = kc * 32 + (L >> 4) * 8 + j;
  dst[tid] = f2fp8(W[g * 128 + k]);
}

// B-frag fp8 swizzle core: [nt][kc(KCs)][lane x 8]; identity k
DEV void swz_ffB_one(int tid, const float* W, int N, int Kd, int KCs, u8* dst){
  int e = tid & 511, chunk = tid >> 9;
  int L = e >> 3, j = e & 7;
  int kc = chunk % KCs; int nt = chunk / KCs;
  int g = nt * 16 + (L & 15);
  int k = kc * 32 + (L >> 4) * 8 + j;
  float v = (g < N && k < Kd) ? W[g * Kd + k] : 0.0f;
  dst[tid] = f2fp8(v);
}

// A-frag fp8 swizzle core: [mt][kc(KCs)][lane x 8]; A[m=mt*16+(L&15)][k]
DEV void swz_ffA_one(int tid, const float* W, int Kd, int KCs, u8* dst){
  int e = tid & 511, chunk = tid >> 9;
  int L = e >> 3, j = e & 7;
  int kc = chunk % KCs; int mt = chunk / KCs;
  int m = mt * 16 + (L & 15);
  int k = kc * 32 + (L >> 4) * 8 + j;
  float v = (k < Kd) ? W[m * Kd + k] : 0.0f;
  dst[tid] = f2fp8(v);
}

// one launch for ALL weight prep (words cvt removed: k_gin reads f32 directly)
__global__ __launch_bounds__(256) void k_pre(
    const float* __restrict__ WhhA, u8* dA, const float* __restrict__ WhhB, u8* dB,
    const float* __restrict__ WhhC, u8* dC, const float* __restrict__ WhhD, u8* dD,
    const float* __restrict__ emb,
    const float* __restrict__ cWihF, const float* __restrict__ cbF,
    const float* __restrict__ cWihB, const float* __restrict__ cbB,
    u8* __restrict__ ctab,
    const float* __restrict__ gWf, const float* __restrict__ gWb,
    u8* __restrict__ dgf, u8* __restrict__ dgb,
    const float* __restrict__ W1, u8* d1, const float* __restrict__ W2, u8* d2,
    const float* __restrict__ W5, u8* d5,
    const float* __restrict__ W3, u8* d3, const float* __restrict__ W4, u8* d4)
{
  const int b = blockIdx.x, tid = threadIdx.x;
  if (b < 4096){                                   // 4 LSTM Whh swizzles
    if (b < 1024)       swz_lstm16_one(b * 256 + tid, WhhA, dA);
    else if (b < 2048)  swz_lstm16_one((b - 1024) * 256 + tid, WhhB, dB);
    else if (b < 3072)  swz_lstm16_one((b - 2048) * 256 + tid, WhhC, dC);
    else                swz_lstm16_one((b - 3072) * 256 + tid, WhhD, dD);
  } else if (b < 4352){                            // char gate table
    int vd = b - 4096;
    ctab_one(vd, tid, emb, (vd >> 7) ? cWihB : cWihF, (vd >> 7) ? cbB : cbF, ctab);
  } else if (b < 5376){                            // word Wih B-frags
    int bb = b - 4352;
    if (bb < 512) swz_gin_one(bb * 256 + tid, gWf, dgf);
    else          swz_gin_one((bb - 512) * 256 + tid, gWb, dgb);
  } else if (b < 6928){                            // FF B-frags
    int bb = b - 5376;
    if (bb < 1024)      swz_ffB_one(bb * 256 + tid, W1, 512, 512, 16, d1);
    else if (bb < 1536) swz_ffB_one((bb - 1024) * 256 + tid, W2, 200, 512, 16, d2);
    else                swz_ffB_one((bb - 1536) * 256 + tid, W5, 12, 256, 8, d5);
  } else {                                         // FF A-frags
    int bb = b - 6928;
    if (bb < 1536) swz_ffA_one(bb * 256 + tid, W3, 712, 24, d3);
    else           swz_ffA_one((bb - 1536) * 256 + tid, W4, 512, 16, d4);
  }
}

// ---------- gin precompute: gin = fp8(x @ Wih^T + b), 4 timesteps/block ----------
// Reads f32 words directly (inline fp8 cvt). Page layout for the 4-row lstm
// consumer: page at ((dir*64+slice4)*200+t)*4096; thread tid reads dword tid*4.
__global__ __launch_bounds__(512) void k_gin(
    const float* __restrict__ words, const u8* __restrict__ wswg_f,
    const u8* __restrict__ wswg_b, const float* __restrict__ bias_f,
    const float* __restrict__ bias_b, u8* __restrict__ gin)
{
  const int blk = blockIdx.x;
  const int d = blk / 800, rem = blk - d * 800;
  const int slice = rem / 50, tq = rem - slice * 50;
  const u8* Wsw = d ? wswg_b : wswg_f;
  const float* bias = d ? bias_b : bias_f;
  __shared__ u8 xs[16 * 136];
  __shared__ u8 sbuf[4 * 4096];
  const int tid = threadIdx.x;
  const int wv = tid >> 6, L = tid & 63;
  const int lrow = L & 15, lq = L >> 4;
  const long* WswV = (const long*)Wsw;

  long wr[8][4];
  #pragma unroll
  for (int nt = 0; nt < 8; ++nt)
    #pragma unroll
    for (int kc = 0; kc < 4; ++kc)
      wr[nt][kc] = WswV[((wv * 8 + nt) * 4 + kc) * 64 + L];
  float bv[8];
  #pragma unroll
  for (int nt = 0; nt < 8; ++nt) bv[nt] = bias[wv * 128 + nt * 16 + lrow];

  for (int i = 0; i < 4; ++i){
    const int t = tq * 4 + i;
    {   // stage f32 x tile -> fp8 LDS (16 rows x 128 cols; 4 floats/thread)
      int r = tid >> 5, c4 = (tid & 31) * 4;
      f32x4 v = *(const f32x4*)&words[((long)(slice * 16 + r) * 200 + t) * 128 + c4];
      *(unsigned*)&xs[r * 136 + c4] = pk4fp8(v.x, v.y, v.z, v.w);
    }
    __syncthreads();
    f32x4 acc[8];
    #pragma unroll
    for (int nt = 0; nt < 8; ++nt) acc[nt] = (f32x4){bv[nt], bv[nt], bv[nt], bv[nt]};
    #pragma unroll
    for (int kc = 0; kc < 4; ++kc){
      long af = *(const long*)&xs[lrow * 136 + kc * 32 + lq * 8];
      #pragma unroll
      for (int nt = 0; nt < 8; ++nt)
        acc[nt] = mfma16f8(af, wr[nt][kc], acc[nt]);
    }
    // acc[nt][r] = gate for row (slice*16 + lq*4 + r), col c = wv*128+nt*16+lrow.
    #pragma unroll
    for (int nt = 0; nt < 8; ++nt){
      int c = wv * 128 + nt * 16 + lrow;
      int gt = c >> 8, hcol = c & 255;
      int base = (hcol >> 4) * 256 + (hcol & 15) * 4 + gt;  // + r*64
      #pragma unroll
      for (int r = 0; r < 4; ++r)
        sbuf[lq * 4096 + base + r * 64] = f2fp8(acc[nt][r]);
    }
    __syncthreads();
    #pragma unroll
    for (int q = 0; q < 4; ++q){
      long ob = ((long)((d * 64 + slice * 4 + q) * 200 + t)) * 4096 + tid * 8;
      *(long*)&gin[ob] = *(const long*)&sbuf[q * 4096 + tid * 8];
    }
    __syncthreads();
  }
}

// ---------- bidirectional LSTM: 256 blocks x 1024 thr, 4 batch rows/block ----
// (frozen at R5 structure: 272 us, MfmaUtil 67%)
template<bool CHARV>
DEV void lstm16_body(u8* abuf, u8* cidxs,
                     const u8* __restrict__ gsrc,     // word: gin4; char: ctab(+dir off)
                     const int* __restrict__ chars,
                     const u8* __restrict__ Wsw,
                     const int* __restrict__ lens,
                     u8* __restrict__ hout,
                     int b0, int hcol0, bool rev, long ginBase)
{
  const int tid = threadIdx.x;
  const int w = tid >> 6, L = tid & 63;
  const int lrow = L & 15, lq = L >> 4;
  const int gcol = w * 16 + lrow;
  const long* WswV = (const long*)Wsw;

  long wr[4][8];
  #pragma unroll
  for (int gt = 0; gt < 4; ++gt)
    #pragma unroll
    for (int kc = 0; kc < 8; ++kc)
      wr[gt][kc] = WswV[(((w * 4 + gt) * 8) + kc) * 64 + L];

  const int mylen = lens[b0 + lq];
  const long hbase = (long)(b0 + lq) * 200 * 512 + hcol0 + gcol;

  float cst = 0.0f;
  u8 hst = 0, houtv = 0;

  for (int e = tid; e < 1120; e += 1024) ((long*)abuf)[e] = 0;   // 2*16*280 B

  if constexpr (CHARV){
    if (tid < 800) cidxs[tid] = (u8)chars[(b0 + tid / 200) * 200 + tid % 200];
  }
  __syncthreads();

  const int t0 = rev ? 199 : 0;
  unsigned gw;
  if constexpr (!CHARV)
    gw = *(const unsigned*)(gsrc + (ginBase + t0) * 4096 + tid * 4);
  else
    gw = *(const unsigned*)&gsrc[((int)cidxs[lq * 200 + t0] * 256 + gcol) * 4];

  for (int tau = 0; tau < 200; ++tau){
    const int t = rev ? (199 - tau) : tau;
    u8* cur = abuf + (tau & 1) * 4480;
    u8* nxt = abuf + ((tau & 1) ^ 1) * 4480;

    f32x4 q = dq8x4((int)gw);
    f32x4 acc[4];
    #pragma unroll
    for (int gt = 0; gt < 4; ++gt)
      acc[gt] = (f32x4){q[gt], q[gt], q[gt], q[gt]};

    {   // prefetch next step's gate dword
      const int tn = (tau < 199) ? (rev ? t - 1 : t + 1) : t;
      if constexpr (!CHARV)
        gw = *(const unsigned*)(gsrc + (ginBase + tn) * 4096 + tid * 4);
      else
        gw = *(const unsigned*)&gsrc[((int)cidxs[lq * 200 + tn] * 256 + gcol) * 4];
    }

    #pragma unroll
    for (int kc = 0; kc < 8; ++kc){
      long af = *(const long*)&cur[lrow * 280 + kc * 32 + lq * 8];
      #pragma unroll
      for (int gt = 0; gt < 4; ++gt)
        acc[gt] = mfma16f8(af, wr[gt][kc], acc[gt]);
    }

    // epilogue: single row (slot 4*lq, r=0)
    const bool mk = t < mylen;
    float gi = acc[0][0], gf = acc[1][0];
    float gg = acc[2][0], go = acc[3][0];
    float cn = fsig(gf) * cst + fsig(gi) * ftanh(gg);
    if (mk) cst = cn;
    float hn = fsig(go) * ftanh(cn);
    u8 p8 = f2fp8(hn);
    if (mk) hst = p8;
    houtv = mk ? p8 : (u8)0;
    nxt[(lq * 4) * 280 + gcol] = hst;
    hout[hbase + (long)t * 512] = houtv;   // fire-and-forget

    lds_barrier();
  }
}

__global__ __launch_bounds__(1024) void k_lstm(
    const int* __restrict__ characters, const u8* __restrict__ gin,
    const u8* __restrict__ ctab,
    const u8* __restrict__ wsw_cf, const u8* __restrict__ wsw_cb,
    const u8* __restrict__ wsw_wf, const u8* __restrict__ wsw_wb,
    const int* __restrict__ len_char, const int* __restrict__ len_word,
    u8* __restrict__ h_char, u8* __restrict__ h_word)
{
  const int dir    = blockIdx.x >> 6;
  const int slice4 = blockIdx.x & 63;
  const int b0 = slice4 * 4;
  __shared__ __align__(16) u8 abuf[2 * 16 * 280];
  __shared__ u8 cidxs[4 * 200];

  if (dir == 0)
    lstm16_body<true>(abuf, cidxs, ctab, characters, wsw_cf,
                      len_char, h_char, b0, 0, false, 0);
  else if (dir == 1)
    lstm16_body<true>(abuf, cidxs, ctab + 131072, characters, wsw_cb,
                      len_char, h_char, b0, 256, true, 0);
  else if (dir == 2)
    lstm16_body<false>(abuf, cidxs, gin, nullptr, wsw_wf,
                       len_word, h_word, b0, 0, false, (long)slice4 * 200);
  else
    lstm16_body<false>(abuf, cidxs, gin, nullptr, wsw_wb,
                       len_word, h_word, b0, 256, true, (long)(64 + slice4) * 200);
}

// ---------- G1+G2 merged (fp8 GEMM into x_cat, zero-fill pad cols) ----------
// 512 threads: 8 waves, wave w owns m-tile w (16 rows); acc[8] = 32 VGPR.
// Same 9KB chunked LDS as R5 -> 4+ blocks/CU co-resident (32 waves/CU).
DEV void g12_body(const u8* __restrict__ A, const u8* __restrict__ Wsw,
                  const float* __restrict__ bias, int N,
                  u8* __restrict__ outp, int ocol0, int m0base, int ntbase, u8* lds)
{
  const int tid = threadIdx.x;               // 512
  const int w = tid >> 6, L = tid & 63;
  const int lrow = L & 15, lq = L >> 4;
  const long* WswV = (const long*)Wsw;
  f32x4 acc[8] = {};
  const int srow = tid >> 2, scol = (tid & 3) * 16;

  // rotated A-tile prefetch: load kc2+1 while kc2's MFMAs run
  i32x4 v0 = *(const i32x4*)&A[(long)(m0base + srow) * 512 + scol];

  for (int kc2 = 0; kc2 < 8; ++kc2){
    *(long*)&lds[srow * 72 + scol]     = ((const long*)&v0)[0];
    *(long*)&lds[srow * 72 + scol + 8] = ((const long*)&v0)[1];
    lds_barrier();
    if (kc2 < 7)
      v0 = *(const i32x4*)&A[(long)(m0base + srow) * 512 + (kc2 + 1) * 64 + scol];
    long af[2];
    #pragma unroll
    for (int kk = 0; kk < 2; ++kk)
      af[kk] = *(const long*)&lds[(w * 16 + lrow) * 72 + kk * 32 + lq * 8];
    #pragma unroll
    for (int kk = 0; kk < 2; ++kk)
      #pragma unroll
      for (int nt = 0; nt < 8; ++nt){
        long bf = WswV[((ntbase + nt) * 16 + kc2 * 2 + kk) * 64 + L];
        acc[nt] = mfma16f8(af[kk], bf, acc[nt]);
      }
    lds_barrier();
  }
  #pragma unroll
  for (int nt = 0; nt < 8; ++nt){
    const int col = (ntbase + nt) * 16 + lrow;
    const bool valid = col < N;
    const float bvv = valid ? bias[col] : 0.0f;
    #pragma unroll
    for (int r = 0; r < 4; ++r){
      float v = fsoftplus(acc[nt][r] + bvv);
      const long row = m0base + w * 16 + lq * 4 + r;
      outp[row * 768 + ocol0 + col] = valid ? f2fp8(v) : (u8)0;
    }
  }
}

__global__ __launch_bounds__(512) void k_g12(
    const u8* __restrict__ hc, const u8* __restrict__ hw,
    const u8* __restrict__ w1, const u8* __restrict__ w2,
    const float* __restrict__ b1, const float* __restrict__ b2,
    u8* __restrict__ xcat)
{
  __shared__ __align__(16) u8 lds[128 * 72];
  const int y = blockIdx.y;
  if (y < 4)
    g12_body(hc, w1, b1, 512, xcat,   0, blockIdx.x * 128, y * 8, lds);
  else
    g12_body(hw, w2, b2, 200, xcat, 512, blockIdx.x * 128, (y - 4) * 8, lds);
}

// ---------- fused tail: logits = sp(sp(sp(xcat@W3+b3)@W4+b4)@W5+b5) ----------
// 512 threads: stage-1 waves own 4 ch-tiles each (acc[4][4] = 64 VGPR);
// same 55KB LDS -> 2 blocks/CU but 16 waves/CU (was 8).
__global__ __launch_bounds__(512) void k_tail(
    const u8* __restrict__ xcat, const u8* __restrict__ w3A,
    const u8* __restrict__ w4A, const u8* __restrict__ w5B,
    const float* __restrict__ b3, const float* __restrict__ b4,
    const float* __restrict__ b5, float* __restrict__ logits)
{
  __shared__ __align__(16) u8 sA[64 * 72];     // x_cat k-chunk stage
  __shared__ __align__(16) u8 x1s[64 * 520];   // [batch][512+8]
  __shared__ __align__(16) u8 x2s[64 * 264];   // [batch][256+8]
  const int tid = threadIdx.x;                 // 512, 8 waves
  const int w = tid >> 6, L = tid & 63;
  const int lrow = L & 15, lq = L >> 4;
  const int m0 = blockIdx.x * 64;
  const long* W3 = (const long*)w3A;
  const long* W4 = (const long*)w4A;
  const long* W5 = (const long*)w5B;

  // ---- stage 1: x1 = sp(xcat @ lin1^T + b3) ; A=W3, B=xcat, D=x1^T ----
  f32x4 acc[4][4];
  #pragma unroll
  for (int mt = 0; mt < 4; ++mt)
    #pragma unroll
    for (int nt = 0; nt < 4; ++nt) acc[mt][nt] = (f32x4){0,0,0,0};
  const int srow = tid >> 3, sc = (tid & 7) * 8;

  long v = *(const long*)&xcat[(long)(m0 + srow) * 768 + sc];
  for (int kc2 = 0; kc2 < 12; ++kc2){
    *(long*)&sA[srow * 72 + sc] = v;
    lds_barrier();
    if (kc2 < 11)
      v = *(const long*)&xcat[(long)(m0 + srow) * 768 + (kc2 + 1) * 64 + sc];
    #pragma unroll
    for (int kk = 0; kk < 2; ++kk){
      long bf[4];
      #pragma unroll
      for (int nt = 0; nt < 4; ++nt)
        bf[nt] = *(const long*)&sA[(nt * 16 + lrow) * 72 + kk * 32 + lq * 8];
      #pragma unroll
      for (int mt = 0; mt < 4; ++mt){
        long af = W3[((w * 4 + mt) * 24 + kc2 * 2 + kk) * 64 + L];
        #pragma unroll
        for (int nt = 0; nt < 4; ++nt)
          acc[mt][nt] = mfma16f8(af, bf[nt], acc[mt][nt]);
      }
    }
    lds_barrier();
  }
  #pragma unroll
  for (int mt = 0; mt < 4; ++mt){
    const int ch0 = (w * 4 + mt) * 16 + lq * 4;
    f32x4 bb = *(const f32x4*)&b3[ch0];
    #pragma unroll
    for (int nt = 0; nt < 4; ++nt){
      const int bat = nt * 16 + lrow;
      unsigned pk = pk4fp8(fsoftplus(acc[mt][nt][0] + bb[0]),
                           fsoftplus(acc[mt][nt][1] + bb[1]),
                           fsoftplus(acc[mt][nt][2] + bb[2]),
                           fsoftplus(acc[mt][nt][3] + bb[3]));
      *(unsigned*)&x1s[bat * 520 + ch0] = pk;
    }
  }
  lds_barrier();

  // ---- stage 2: x2 = sp(x1 @ lin2^T + b4) ; A=W4, B=x1, D=x2^T ----
  f32x4 a2[2][4];
  #pragma unroll
  for (int mt = 0; mt < 2; ++mt)
    #pragma unroll
    for (int nt = 0; nt < 4; ++nt) a2[mt][nt] = (f32x4){0,0,0,0};
  for (int kc = 0; kc < 16; ++kc){
    long bf[4];
    #pragma unroll
    for (int nt = 0; nt < 4; ++nt)
      bf[nt] = *(const long*)&x1s[(nt * 16 + lrow) * 520 + kc * 32 + lq * 8];
    #pragma unroll
    for (int mt = 0; mt < 2; ++mt){
      long af = W4[((w * 2 + mt) * 16 + kc) * 64 + L];
      #pragma unroll
      for (int nt = 0; nt < 4; ++nt)
        a2[mt][nt] = mfma16f8(af, bf[nt], a2[mt][nt]);
    }
  }
  #pragma unroll
  for (int mt = 0; mt < 2; ++mt){
    const int ch0 = (w * 2 + mt) * 16 + lq * 4;
    f32x4 bb = *(const f32x4*)&b4[ch0];
    #pragma unroll
    for (int nt = 0; nt < 4; ++nt){
      const int bat = nt * 16 + lrow;
      unsigned pk = pk4fp8(fsoftplus(a2[mt][nt][0] + bb[0]),
                           fsoftplus(a2[mt][nt][1] + bb[1]),
                           fsoftplus(a2[mt][nt][2] + bb[2]),
                           fsoftplus(a2[mt][nt][3] + bb[3]));
      *(unsigned*)&x2s[bat * 264 + ch0] = pk;
    }
  }
  lds_barrier();

  // ---- stage 3: logits = sp(x2 @ tag^T + b5) ; waves 0-3 only ----
  if (w < 4){
    f32x4 a3 = (f32x4){0,0,0,0};
    #pragma unroll
    for (int kc = 0; kc < 8; ++kc){
      long af = *(const long*)&x2s[(w * 16 + lrow) * 264 + kc * 32 + lq * 8];
      long bf = W5[kc * 64 + L];
      a3 = mfma16f8(af, bf, a3);
    }
    if (lrow < 12){
      float bb = b5[lrow];
      #pragma unroll
      for (int r = 0; r < 4; ++r)
        logits[(long)(m0 + w * 16 + lq * 4 + r) * 12 + lrow] = fsoftplus(a3[r] + bb);
    }
  }
}

// ---------- CRF NLL: one wave per batch row; shfl alpha exchange ----------
__global__ void k_crf(const float* __restrict__ logits, const int* __restrict__ tags,
                      const int* __restrict__ lens, const float* __restrict__ trans,
                      float* __restrict__ nll)
{
  const int b = blockIdx.x;
  const int lane = threadIdx.x;            // 64
  __shared__ float sl[2400];               // [t][12]
  for (int e = lane; e < 2400; e += 64) sl[e] = logits[(long)b * 2400 + e];
  const int lj = (lane < 12) ? lane : 0;   // lanes >=12 mirror lane 0 (harmless)
  float tcol[12];
  #pragma unroll
  for (int i = 0; i < 12; ++i) tcol[i] = trans[i * 12 + lj];
  const int len = lens[b];
  float alpha = 0.0f;
  __syncthreads();

  for (int t = 0; t < len; ++t){
    float av[12];
    #pragma unroll
    for (int i = 0; i < 12; ++i)
      av[i] = __shfl(alpha, i, 64) + tcol[i];
    float mx = av[0];
    #pragma unroll
    for (int i = 1; i < 12; ++i) mx = fmaxf(mx, av[i]);
    float ss = 0.0f;
    #pragma unroll
    for (int i = 0; i < 12; ++i)
      ss += __builtin_amdgcn_exp2f(1.4426950408889634f * (av[i] - mx));
    alpha = sl[t * 12 + lj] + mx + 0.69314718055994531f * __builtin_amdgcn_logf(ss);
  }

  // total = logsumexp_j(alpha_j + trans[j][STOP])
  float tv = alpha + trans[lj * 12 + 11];
  float tmax = tv;
  #pragma unroll
  for (int i = 0; i < 12; ++i) tmax = fmaxf(tmax, __shfl(tv, i, 64));
  float tss = 0.0f;
  #pragma unroll
  for (int i = 0; i < 12; ++i)
    tss += __builtin_amdgcn_exp2f(1.4426950408889634f * (__shfl(tv, i, 64) - tmax));

  // real path score
  float rs = 0.0f;
  for (int t = lane; t < len; t += 64){
    int tg = tags[b * 200 + t];
    int pv = (t == 0) ? 10 : tags[b * 200 + t - 1];                 // START=10
    rs += sl[t * 12 + tg] + trans[pv * 12 + tg];
  }
  #pragma unroll
  for (int off = 32; off > 0; off >>= 1) rs += __shfl_down(rs, off, 64);
  if (lane == 0){
    float total = tmax + 0.69314718055994531f * __builtin_amdgcn_logf(tss);
    rs += trans[tags[b * 200 + len - 1] * 12 + 11];
    nll[b] = total - rs;
  }
}

__global__ void k_sum(const float* __restrict__ nll, float* __restrict__ out){
  __shared__ float red[256];
  int t = threadIdx.x;
  red[t] = nll[t];
  __syncthreads();
  for (int s = 128; s > 0; s >>= 1){
    if (t < s) red[t] += red[t + s];
    __syncthreads();
  }
  if (t == 0) out[0] = red[0];
}

// ---------- launcher ----------
extern "C" void kernel_launch(void* const* d_in, const int* in_sizes, int n_in,
                              void* d_out, int out_size, void* d_ws, size_t ws_size,
                              hipStream_t stream)
{
  (void)in_sizes; (void)n_in; (void)out_size; (void)ws_size;
  const int*   characters = (const int*)  d_in[0];
  const float* words      = (const float*)d_in[1];
  const int*   tags       = (const int*)  d_in[2];
  const int*   len_char   = (const int*)  d_in[3];
  const int*   len_word   = (const int*)  d_in[4];
  const float* char_emb   = (const float*)d_in[5];
  const float* char_Wih_f = (const float*)d_in[6];
  const float* char_Whh_f = (const float*)d_in[7];
  const float* char_b_f   = (const float*)d_in[8];
  const float* char_Wih_b = (const float*)d_in[9];
  const float* char_Whh_b = (const float*)d_in[10];
  const float* char_b_b   = (const float*)d_in[11];
  const float* char_lin_W = (const float*)d_in[12];
  const float* char_lin_b = (const float*)d_in[13];
  const float* word_Wih_f = (const float*)d_in[14];
  const float* word_Whh_f = (const float*)d_in[15];
  const float* word_b_f   = (const float*)d_in[16];
  const float* word_Wih_b = (const float*)d_in[17];
  const float* word_Whh_b = (const float*)d_in[18];
  const float* word_b_b   = (const float*)d_in[19];
  const float* word_lin_W = (const float*)d_in[20];
  const float* word_lin_b = (const float*)d_in[21];
  const float* lin1_W     = (const float*)d_in[22];
  const float* lin1_b     = (const float*)d_in[23];
  const float* lin2_W     = (const float*)d_in[24];
  const float* lin2_b     = (const float*)d_in[25];
  const float* tag_W      = (const float*)d_in[26];
  const float* tag_b      = (const float*)d_in[27];
  const float* trans      = (const float*)d_in[28];

  char* ws = (char*)d_ws;
  size_t off = 0;
  auto take = [&](size_t bytes) -> char* {
    char* p = ws + off;
    off = (off + bytes + 511) & ~(size_t)511;
    return p;
  };
  u8*   wsw_cf   = (u8*)take((size_t)262144);      // [w16][gt4][kc8][64x8B]
  u8*   wsw_cb   = (u8*)take((size_t)262144);
  u8*   wsw_wf   = (u8*)take((size_t)262144);
  u8*   wsw_wb   = (u8*)take((size_t)262144);
  u8*   ctab     = (u8*)take((size_t)262144);      // [dir2][v128][gcol256][gt4]
  u8*   wswgin_f = (u8*)take((size_t)64*4*512);
  u8*   wswgin_b = (u8*)take((size_t)64*4*512);
  u8*   wswg1    = (u8*)take((size_t)32*16*512);   // B-frag (char_lin)
  u8*   wswg2    = (u8*)take((size_t)16*16*512);   // B-frag (word_lin)
  u8*   wswg3    = (u8*)take((size_t)32*24*512);   // A-frag (lin1)
  u8*   wswg4    = (u8*)take((size_t)16*16*512);   // A-frag (lin2)
  u8*   wswg5    = (u8*)take((size_t)1*8*512);     // B-frag (tag)
  float* logits  = (float*)take((size_t)51200*12*4);
  float* nll     = (float*)take((size_t)256*4);
  u8*   h_char   = (u8*)take((size_t)51200*512);   // 25 MB fp8 (identity cols)
  u8*   h_word   = (u8*)take((size_t)51200*512);   // 25 MB fp8
  u8*   gin      = (u8*)take((size_t)105*1024*1024);  // reused post-lstm
  u8*   x_cat    = gin;                            // 51200*768 = 38.4 MB

  // preprocessing: ONE launch for all weight prep
  k_pre<<<8976, 256, 0, stream>>>(
      char_Whh_f, wsw_cf, char_Whh_b, wsw_cb, word_Whh_f, wsw_wf, word_Whh_b, wsw_wb,
      char_emb, char_Wih_f, char_b_f, char_Wih_b, char_b_b, ctab,
      word_Wih_f, word_Wih_b, wswgin_f, wswgin_b,
      char_lin_W, wswg1, word_lin_W, wswg2, tag_W, wswg5,
      lin1_W, wswg3, lin2_W, wswg4);

  // gin precompute (word input projection, f32 source), 4-row-page layout
  k_gin<<<1600, 512, 0, stream>>>(words, wswgin_f, wswgin_b, word_b_f, word_b_b, gin);

  // recurrences: 256 blocks x 1024 threads (4 batch rows per block)
  k_lstm<<<256, 1024, 0, stream>>>(characters, gin, ctab,
                                   wsw_cf, wsw_cb, wsw_wf, wsw_wb,
                                   len_char, len_word, h_char, h_word);

  // feed-forward: G1+G2 then fused G3+G4+G5, both 512-thread (2x waves/CU)
  k_g12<<<dim3(400, 6), 512, 0, stream>>>(h_char, h_word, wswg1, wswg2,
                                          char_lin_b, word_lin_b, x_cat);
  k_tail<<<800, 512, 0, stream>>>(x_cat, wswg3, wswg4, wswg5,
                                  lin1_b, lin2_b, tag_b, logits);

  // CRF
  k_crf<<<256, 64, 0, stream>>>(logits, tags, len_char, trans, nll);
  k_sum<<<1, 256, 0, stream>>>(nll, (float*)d_out);
}

// Round 13
// 644.753 us; speedup vs baseline: 1.0791x; 1.0791x over previous
//
#include <hip/hip_runtime.h>
#include <cstdint>

// ---------- types / helpers ----------
typedef __attribute__((ext_vector_type(8))) short short8;
typedef __attribute__((ext_vector_type(4))) float f32x4;
typedef __attribute__((ext_vector_type(2))) float f32x2;
typedef __attribute__((ext_vector_type(4))) int i32x4;
typedef unsigned short us16;
typedef unsigned char u8;

#define DEV __device__ __forceinline__

DEV u8 f2fp8(float f){      // OCP e4m3fn via HW cvt (RNE, saturating)
  int p = __builtin_amdgcn_cvt_pk_fp8_f32(f, f, 0, false);
  return (u8)(p & 0xFF);
}
template<int SEL> DEV float fp8tof(int dw){
#if __has_builtin(__builtin_amdgcn_cvt_f32_fp8)
  return __builtin_amdgcn_cvt_f32_fp8(dw, SEL);
#else
  int b = (dw >> (8*SEL)) & 255;
  int e = (b>>3)&15, m = b&7;
  float v;
  if (e){ union{unsigned u; float f;} x; x.u = (unsigned)(((e+120)<<23) | (m<<20)); v = x.f; }
  else v = (float)m * 0.001953125f;
  return (b & 128) ? -v : v;
#endif
}
DEV f32x4 dq8x4(int dw){
#if __has_builtin(__builtin_amdgcn_cvt_pk_f32_fp8)
  f32x2 lo = __builtin_amdgcn_cvt_pk_f32_fp8(dw, false);
  f32x2 hi = __builtin_amdgcn_cvt_pk_f32_fp8(dw, true);
  return (f32x4){lo.x, lo.y, hi.x, hi.y};
#else
  return (f32x4){fp8tof<0>(dw), fp8tof<1>(dw), fp8tof<2>(dw), fp8tof<3>(dw)};
#endif
}
DEV float fsig(float x){
  float e = __builtin_amdgcn_exp2f(-1.4426950408889634f * x);
  return __builtin_amdgcn_rcpf(1.0f + e);
}
DEV float ftanh(float x){
  float e = __builtin_amdgcn_exp2f(-2.8853900817779268f * x);
  return fmaf(2.0f, __builtin_amdgcn_rcpf(1.0f + e), -1.0f);
}
DEV float fsoftplus(float x){
  float ax = fabsf(x);
  float e = __builtin_amdgcn_exp2f(-1.4426950408889634f * ax);
  float l = 0.69314718055994531f * __builtin_amdgcn_logf(1.0f + e);
  return fmaxf(x, 0.0f) + l;
}
DEV f32x4 mfma16f8(long a, long b, f32x4 c){
  return __builtin_amdgcn_mfma_f32_16x16x32_fp8_fp8(a, b, c, 0, 0, 0);
}
DEV unsigned pk4fp8(float a, float b, float c, float d){
  unsigned lo = (unsigned)__builtin_amdgcn_cvt_pk_fp8_f32(a, b, 0, false) & 0xFFFFu;
  unsigned hi = (unsigned)__builtin_amdgcn_cvt_pk_fp8_f32(c, d, 0, false) & 0xFFFFu;
  return lo | (hi << 16);
}

// Raw LDS barrier: drains LDS ops only; global loads/stores float across.
DEV void lds_barrier(){
  asm volatile("s_waitcnt lgkmcnt(0)" ::: "memory");
  __builtin_amdgcn_s_barrier();
  asm volatile("" ::: "memory");
}

// Dims: B=256, T=WN=200, HH=256/dir, gates=1024, tags K=12.
// MFMA 16x16x32 fragments: A: lane L holds A[m=L&15][k=(L>>4)*8+j];
// B: lane L holds B[k=(L>>4)*8+j][n=L&15]; D: lane L reg r = D[(L>>4)*4+r][L&15].
// k_lstm: 4 batch rows per block, row j in A-slot 4j (1-row epilogue/thread).
// k_g12/k_tail: R5 chunked 256-thread structure (verified optimum; fusion,
// full-LDS staging, and 512-thread widening all regressed 20-47us).

// ---------- merged preprocessing bodies ----------

// LSTM Whh B-frag swizzle (16-wave layout): [w(16)][gt(4)][kc(8)][lane x 8B]
DEV void swz_lstm16_one(int tid, const float* __restrict__ W, u8* __restrict__ dst){
  int e = tid & 511, chunk = tid >> 9;       // chunk = w*32 + gt*8 + kc
  int L = e >> 3, j = e & 7;
  int kc = chunk & 7, gt = (chunk >> 3) & 3, w = chunk >> 5;
  int g = gt * 256 + w * 16 + (L & 15);
  int k = kc * 32 + (L >> 4) * 8 + j;
  dst[tid] = f2fp8(W[g * 256 + k]);
}

// char gate table: ctab[dir][v][gcol(256)][gt(4)] fp8 = fp8(emb[v]@Wih^T + b)
DEV void ctab_one(int vd, int gcol, const float* __restrict__ emb,
                  const float* __restrict__ Wih, const float* __restrict__ bb,
                  u8* __restrict__ ctab){
  int v = vd & 127, dir = vd >> 7;
  float val[4];
  #pragma unroll
  for (int gt = 0; gt < 4; ++gt){
    int g = gt * 256 + gcol;
    float s = bb[g];
    for (int k = 0; k < 30; ++k) s += emb[v * 30 + k] * Wih[g * 30 + k];
    val[gt] = s;
  }
  unsigned pk = pk4fp8(val[0], val[1], val[2], val[3]);
  *(unsigned*)&ctab[((dir * 128 + v) * 256 + gcol) * 4] = pk;
}

// Wih (word) B-frag swizzle: [ntile(64)][kc(4)][lane x 8B]
DEV void swz_gin_one(int tid, const float* __restrict__ W, u8* __restrict__ dst){
  int e = tid & 511, chunk = tid >> 9;
  int L = e >> 3, j = e & 7;
  int kc = chunk & 3, ntile = chunk >> 2;
  int g = ntile * 16 + (L & 15);
  int k = kc * 32 + (L >> 4) * 8 + j;
  dst[tid] = f2fp8(W[g * 128 + k]);
}

// B-frag fp8 swizzle core: [nt][kc(KCs)][lane x 8]; identity k
DEV void swz_ffB_one(int tid, const float* W, int N, int Kd, int KCs, u8* dst){
  int e = tid & 511, chunk = tid >> 9;
  int L = e >> 3, j = e & 7;
  int kc = chunk % KCs; int nt = chunk / KCs;
  int g = nt * 16 + (L & 15);
  int k = kc * 32 + (L >> 4) * 8 + j;
  float v = (g < N && k < Kd) ? W[g * Kd + k] : 0.0f;
  dst[tid] = f2fp8(v);
}

// A-frag fp8 swizzle core: [mt][kc(KCs)][lane x 8]; A[m=mt*16+(L&15)][k]
DEV void swz_ffA_one(int tid, const float* W, int Kd, int KCs, u8* dst){
  int e = tid & 511, chunk = tid >> 9;
  int L = e >> 3, j = e & 7;
  int kc = chunk % KCs; int mt = chunk / KCs;
  int m = mt * 16 + (L & 15);
  int k = kc * 32 + (L >> 4) * 8 + j;
  float v = (k < Kd) ? W[m * Kd + k] : 0.0f;
  dst[tid] = f2fp8(v);
}

// one launch for ALL weight prep (words cvt removed: k_gin reads f32 directly)
__global__ __launch_bounds__(256) void k_pre(
    const float* __restrict__ WhhA, u8* dA, const float* __restrict__ WhhB, u8* dB,
    const float* __restrict__ WhhC, u8* dC, const float* __restrict__ WhhD, u8* dD,
    const float* __restrict__ emb,
    const float* __restrict__ cWihF, const float* __restrict__ cbF,
    const float* __restrict__ cWihB, const float* __restrict__ cbB,
    u8* __restrict__ ctab,
    const float* __restrict__ gWf, const float* __restrict__ gWb,
    u8* __restrict__ dgf, u8* __restrict__ dgb,
    const float* __restrict__ W1, u8* d1, const float* __restrict__ W2, u8* d2,
    const float* __restrict__ W5, u8* d5,
    const float* __restrict__ W3, u8* d3, const float* __restrict__ W4, u8* d4)
{
  const int b = blockIdx.x, tid = threadIdx.x;
  if (b < 4096){                                   // 4 LSTM Whh swizzles
    if (b < 1024)       swz_lstm16_one(b * 256 + tid, WhhA, dA);
    else if (b < 2048)  swz_lstm16_one((b - 1024) * 256 + tid, WhhB, dB);
    else if (b < 3072)  swz_lstm16_one((b - 2048) * 256 + tid, WhhC, dC);
    else                swz_lstm16_one((b - 3072) * 256 + tid, WhhD, dD);
  } else if (b < 4352){                            // char gate table
    int vd = b - 4096;
    ctab_one(vd, tid, emb, (vd >> 7) ? cWihB : cWihF, (vd >> 7) ? cbB : cbF, ctab);
  } else if (b < 5376){                            // word Wih B-frags
    int bb = b - 4352;
    if (bb < 512) swz_gin_one(bb * 256 + tid, gWf, dgf);
    else          swz_gin_one((bb - 512) * 256 + tid, gWb, dgb);
  } else if (b < 6928){                            // FF B-frags
    int bb = b - 5376;
    if (bb < 1024)      swz_ffB_one(bb * 256 + tid, W1, 512, 512, 16, d1);
    else if (bb < 1536) swz_ffB_one((bb - 1024) * 256 + tid, W2, 200, 512, 16, d2);
    else                swz_ffB_one((bb - 1536) * 256 + tid, W5, 12, 256, 8, d5);
  } else {                                         // FF A-frags
    int bb = b - 6928;
    if (bb < 1536) swz_ffA_one(bb * 256 + tid, W3, 712, 24, d3);
    else           swz_ffA_one((bb - 1536) * 256 + tid, W4, 512, 16, d4);
  }
}

// ---------- gin precompute: gin = fp8(x @ Wih^T + b), 4 timesteps/block ----------
// Reads f32 words directly (inline fp8 cvt). Page layout for the 4-row lstm
// consumer: page at ((dir*64+slice4)*200+t)*4096; thread tid reads dword tid*4.
__global__ __launch_bounds__(512) void k_gin(
    const float* __restrict__ words, const u8* __restrict__ wswg_f,
    const u8* __restrict__ wswg_b, const float* __restrict__ bias_f,
    const float* __restrict__ bias_b, u8* __restrict__ gin)
{
  const int blk = blockIdx.x;
  const int d = blk / 800, rem = blk - d * 800;
  const int slice = rem / 50, tq = rem - slice * 50;
  const u8* Wsw = d ? wswg_b : wswg_f;
  const float* bias = d ? bias_b : bias_f;
  __shared__ u8 xs[16 * 136];
  __shared__ u8 sbuf[4 * 4096];
  const int tid = threadIdx.x;
  const int wv = tid >> 6, L = tid & 63;
  const int lrow = L & 15, lq = L >> 4;
  const long* WswV = (const long*)Wsw;

  long wr[8][4];
  #pragma unroll
  for (int nt = 0; nt < 8; ++nt)
    #pragma unroll
    for (int kc = 0; kc < 4; ++kc)
      wr[nt][kc] = WswV[((wv * 8 + nt) * 4 + kc) * 64 + L];
  float bv[8];
  #pragma unroll
  for (int nt = 0; nt < 8; ++nt) bv[nt] = bias[wv * 128 + nt * 16 + lrow];

  for (int i = 0; i < 4; ++i){
    const int t = tq * 4 + i;
    {   // stage f32 x tile -> fp8 LDS (16 rows x 128 cols; 4 floats/thread)
      int r = tid >> 5, c4 = (tid & 31) * 4;
      f32x4 v = *(const f32x4*)&words[((long)(slice * 16 + r) * 200 + t) * 128 + c4];
      *(unsigned*)&xs[r * 136 + c4] = pk4fp8(v.x, v.y, v.z, v.w);
    }
    __syncthreads();
    f32x4 acc[8];
    #pragma unroll
    for (int nt = 0; nt < 8; ++nt) acc[nt] = (f32x4){bv[nt], bv[nt], bv[nt], bv[nt]};
    #pragma unroll
    for (int kc = 0; kc < 4; ++kc){
      long af = *(const long*)&xs[lrow * 136 + kc * 32 + lq * 8];
      #pragma unroll
      for (int nt = 0; nt < 8; ++nt)
        acc[nt] = mfma16f8(af, wr[nt][kc], acc[nt]);
    }
    // acc[nt][r] = gate for row (slice*16 + lq*4 + r), col c = wv*128+nt*16+lrow.
    #pragma unroll
    for (int nt = 0; nt < 8; ++nt){
      int c = wv * 128 + nt * 16 + lrow;
      int gt = c >> 8, hcol = c & 255;
      int base = (hcol >> 4) * 256 + (hcol & 15) * 4 + gt;  // + r*64
      #pragma unroll
      for (int r = 0; r < 4; ++r)
        sbuf[lq * 4096 + base + r * 64] = f2fp8(acc[nt][r]);
    }
    __syncthreads();
    #pragma unroll
    for (int q = 0; q < 4; ++q){
      long ob = ((long)((d * 64 + slice * 4 + q) * 200 + t)) * 4096 + tid * 8;
      *(long*)&gin[ob] = *(const long*)&sbuf[q * 4096 + tid * 8];
    }
    __syncthreads();
  }
}

// ---------- bidirectional LSTM: 256 blocks x 1024 thr, 4 batch rows/block ----
// (frozen at R5 structure: 272 us, MfmaUtil 67%)
template<bool CHARV>
DEV void lstm16_body(u8* abuf, u8* cidxs,
                     const u8* __restrict__ gsrc,     // word: gin4; char: ctab(+dir off)
                     const int* __restrict__ chars,
                     const u8* __restrict__ Wsw,
                     const int* __restrict__ lens,
                     u8* __restrict__ hout,
                     int b0, int hcol0, bool rev, long ginBase)
{
  const int tid = threadIdx.x;
  const int w = tid >> 6, L = tid & 63;
  const int lrow = L & 15, lq = L >> 4;
  const int gcol = w * 16 + lrow;
  const long* WswV = (const long*)Wsw;

  long wr[4][8];
  #pragma unroll
  for (int gt = 0; gt < 4; ++gt)
    #pragma unroll
    for (int kc = 0; kc < 8; ++kc)
      wr[gt][kc] = WswV[(((w * 4 + gt) * 8) + kc) * 64 + L];

  const int mylen = lens[b0 + lq];
  const long hbase = (long)(b0 + lq) * 200 * 512 + hcol0 + gcol;

  float cst = 0.0f;
  u8 hst = 0, houtv = 0;

  for (int e = tid; e < 1120; e += 1024) ((long*)abuf)[e] = 0;   // 2*16*280 B

  if constexpr (CHARV){
    if (tid < 800) cidxs[tid] = (u8)chars[(b0 + tid / 200) * 200 + tid % 200];
  }
  __syncthreads();

  const int t0 = rev ? 199 : 0;
  unsigned gw;
  if constexpr (!CHARV)
    gw = *(const unsigned*)(gsrc + (ginBase + t0) * 4096 + tid * 4);
  else
    gw = *(const unsigned*)&gsrc[((int)cidxs[lq * 200 + t0] * 256 + gcol) * 4];

  for (int tau = 0; tau < 200; ++tau){
    const int t = rev ? (199 - tau) : tau;
    u8* cur = abuf + (tau & 1) * 4480;
    u8* nxt = abuf + ((tau & 1) ^ 1) * 4480;

    f32x4 q = dq8x4((int)gw);
    f32x4 acc[4];
    #pragma unroll
    for (int gt = 0; gt < 4; ++gt)
      acc[gt] = (f32x4){q[gt], q[gt], q[gt], q[gt]};

    {   // prefetch next step's gate dword
      const int tn = (tau < 199) ? (rev ? t - 1 : t + 1) : t;
      if constexpr (!CHARV)
        gw = *(const unsigned*)(gsrc + (ginBase + tn) * 4096 + tid * 4);
      else
        gw = *(const unsigned*)&gsrc[((int)cidxs[lq * 200 + tn] * 256 + gcol) * 4];
    }

    #pragma unroll
    for (int kc = 0; kc < 8; ++kc){
      long af = *(const long*)&cur[lrow * 280 + kc * 32 + lq * 8];
      #pragma unroll
      for (int gt = 0; gt < 4; ++gt)
        acc[gt] = mfma16f8(af, wr[gt][kc], acc[gt]);
    }

    // epilogue: single row (slot 4*lq, r=0)
    const bool mk = t < mylen;
    float gi = acc[0][0], gf = acc[1][0];
    float gg = acc[2][0], go = acc[3][0];
    float cn = fsig(gf) * cst + fsig(gi) * ftanh(gg);
    if (mk) cst = cn;
    float hn = fsig(go) * ftanh(cn);
    u8 p8 = f2fp8(hn);
    if (mk) hst = p8;
    houtv = mk ? p8 : (u8)0;
    nxt[(lq * 4) * 280 + gcol] = hst;
    hout[hbase + (long)t * 512] = houtv;   // fire-and-forget

    lds_barrier();
  }
}

__global__ __launch_bounds__(1024) void k_lstm(
    const int* __restrict__ characters, const u8* __restrict__ gin,
    const u8* __restrict__ ctab,
    const u8* __restrict__ wsw_cf, const u8* __restrict__ wsw_cb,
    const u8* __restrict__ wsw_wf, const u8* __restrict__ wsw_wb,
    const int* __restrict__ len_char, const int* __restrict__ len_word,
    u8* __restrict__ h_char, u8* __restrict__ h_word)
{
  const int dir    = blockIdx.x >> 6;
  const int slice4 = blockIdx.x & 63;
  const int b0 = slice4 * 4;
  __shared__ __align__(16) u8 abuf[2 * 16 * 280];
  __shared__ u8 cidxs[4 * 200];

  if (dir == 0)
    lstm16_body<true>(abuf, cidxs, ctab, characters, wsw_cf,
                      len_char, h_char, b0, 0, false, 0);
  else if (dir == 1)
    lstm16_body<true>(abuf, cidxs, ctab + 131072, characters, wsw_cb,
                      len_char, h_char, b0, 256, true, 0);
  else if (dir == 2)
    lstm16_body<false>(abuf, cidxs, gin, nullptr, wsw_wf,
                       len_word, h_word, b0, 0, false, (long)slice4 * 200);
  else
    lstm16_body<false>(abuf, cidxs, gin, nullptr, wsw_wb,
                       len_word, h_word, b0, 256, true, (long)(64 + slice4) * 200);
}

// ---------- G1+G2 merged (fp8 GEMM into x_cat, zero-fill pad cols) ----------
// R5 chunked structure (9KB LDS, 2 blocks/CU).
DEV void g12_body(const u8* __restrict__ A, const u8* __restrict__ Wsw,
                  const float* __restrict__ bias, int N,
                  u8* __restrict__ outp, int ocol0, int m0base, int ntbase, u8* lds)
{
  const int tid = threadIdx.x;
  const int w = tid >> 6, L = tid & 63;
  const int lrow = L & 15, lq = L >> 4;
  const long* WswV = (const long*)Wsw;
  f32x4 acc[8][2] = {};
  const int srow = tid >> 1, scol = (tid & 1) * 32;

  // rotated A-tile prefetch: load kc2+1 while kc2's MFMAs run
  i32x4 v0 = *(const i32x4*)&A[(long)(m0base + srow) * 512 + scol];
  i32x4 v1 = *(const i32x4*)&A[(long)(m0base + srow) * 512 + scol + 16];

  for (int kc2 = 0; kc2 < 8; ++kc2){
    *(long*)&lds[srow * 72 + scol]      = ((const long*)&v0)[0];
    *(long*)&lds[srow * 72 + scol + 8]  = ((const long*)&v0)[1];
    *(long*)&lds[srow * 72 + scol + 16] = ((const long*)&v1)[0];
    *(long*)&lds[srow * 72 + scol + 24] = ((const long*)&v1)[1];
    lds_barrier();
    if (kc2 < 7){
      const long ab = (long)(m0base + srow) * 512 + (kc2 + 1) * 64 + scol;
      v0 = *(const i32x4*)&A[ab];
      v1 = *(const i32x4*)&A[ab + 16];
    }
    long af[2][2];
    #pragma unroll
    for (int m0 = 0; m0 < 2; ++m0)
      #pragma unroll
      for (int kk = 0; kk < 2; ++kk)
        af[m0][kk] = *(const long*)&lds[(w * 32 + m0 * 16 + lrow) * 72 + kk * 32 + lq * 8];
    #pragma unroll
    for (int kk = 0; kk < 2; ++kk)
      #pragma unroll
      for (int nt = 0; nt < 8; ++nt){
        long bf = WswV[((ntbase + nt) * 16 + kc2 * 2 + kk) * 64 + L];
        acc[nt][0] = mfma16f8(af[0][kk], bf, acc[nt][0]);
        acc[nt][1] = mfma16f8(af[1][kk], bf, acc[nt][1]);
      }
    lds_barrier();
  }
  #pragma unroll
  for (int nt = 0; nt < 8; ++nt){
    const int col = (ntbase + nt) * 16 + lrow;
    const bool valid = col < N;
    const float bvv = valid ? bias[col] : 0.0f;
    #pragma unroll
    for (int m0 = 0; m0 < 2; ++m0){
      #pragma unroll
      for (int r = 0; r < 4; ++r){
        float v = fsoftplus(acc[nt][m0][r] + bvv);
        const long row = m0base + w * 32 + m0 * 16 + lq * 4 + r;
        outp[row * 768 + ocol0 + col] = valid ? f2fp8(v) : (u8)0;
      }
    }
  }
}

__global__ __launch_bounds__(256) void k_g12(
    const u8* __restrict__ hc, const u8* __restrict__ hw,
    const u8* __restrict__ w1, const u8* __restrict__ w2,
    const float* __restrict__ b1, const float* __restrict__ b2,
    u8* __restrict__ xcat)
{
  __shared__ __align__(16) u8 lds[128 * 72];
  const int y = blockIdx.y;
  if (y < 4)
    g12_body(hc, w1, b1, 512, xcat,   0, blockIdx.x * 128, y * 8, lds);
  else
    g12_body(hw, w2, b2, 200, xcat, 512, blockIdx.x * 128, (y - 4) * 8, lds);
}

// ---------- fused tail: logits = sp(sp(sp(xcat@W3+b3)@W4+b4)@W5+b5) ----------
// R5 chunked structure (50KB LDS, 2 blocks/CU).
__global__ __launch_bounds__(256, 2) void k_tail(
    const u8* __restrict__ xcat, const u8* __restrict__ w3A,
    const u8* __restrict__ w4A, const u8* __restrict__ w5B,
    const float* __restrict__ b3, const float* __restrict__ b4,
    const float* __restrict__ b5, float* __restrict__ logits)
{
  __shared__ __align__(16) u8 sA[64 * 72];     // x_cat k-chunk stage
  __shared__ __align__(16) u8 x1s[64 * 520];   // [batch][512+8]
  __shared__ __align__(16) u8 x2s[64 * 264];   // [batch][256+8]
  const int tid = threadIdx.x;
  const int w = tid >> 6, L = tid & 63;
  const int lrow = L & 15, lq = L >> 4;
  const int m0 = blockIdx.x * 64;
  const long* W3 = (const long*)w3A;
  const long* W4 = (const long*)w4A;
  const long* W5 = (const long*)w5B;

  // ---- stage 1: x1 = sp(xcat @ lin1^T + b3) ; A=W3, B=xcat, D=x1^T ----
  f32x4 acc[8][4];
  #pragma unroll
  for (int mt = 0; mt < 8; ++mt)
    #pragma unroll
    for (int nt = 0; nt < 4; ++nt) acc[mt][nt] = (f32x4){0,0,0,0};
  const int srow = tid >> 2, sc = (tid & 3) * 16;

  i32x4 v = *(const i32x4*)&xcat[(long)(m0 + srow) * 768 + sc];
  for (int kc2 = 0; kc2 < 12; ++kc2){
    *(long*)&sA[srow * 72 + sc]     = ((const long*)&v)[0];
    *(long*)&sA[srow * 72 + sc + 8] = ((const long*)&v)[1];
    lds_barrier();
    if (kc2 < 11)
      v = *(const i32x4*)&xcat[(long)(m0 + srow) * 768 + (kc2 + 1) * 64 + sc];
    #pragma unroll
    for (int kk = 0; kk < 2; ++kk){
      long bf[4];
      #pragma unroll
      for (int nt = 0; nt < 4; ++nt)
        bf[nt] = *(const long*)&sA[(nt * 16 + lrow) * 72 + kk * 32 + lq * 8];
      #pragma unroll
      for (int mt = 0; mt < 8; ++mt){
        long af = W3[((w * 8 + mt) * 24 + kc2 * 2 + kk) * 64 + L];
        #pragma unroll
        for (int nt = 0; nt < 4; ++nt)
          acc[mt][nt] = mfma16f8(af, bf[nt], acc[mt][nt]);
      }
    }
    lds_barrier();
  }
  #pragma unroll
  for (int mt = 0; mt < 8; ++mt){
    const int ch0 = (w * 8 + mt) * 16 + lq * 4;
    f32x4 bb = *(const f32x4*)&b3[ch0];
    #pragma unroll
    for (int nt = 0; nt < 4; ++nt){
      const int bat = nt * 16 + lrow;
      unsigned pk = pk4fp8(fsoftplus(acc[mt][nt][0] + bb[0]),
                           fsoftplus(acc[mt][nt][1] + bb[1]),
                           fsoftplus(acc[mt][nt][2] + bb[2]),
                           fsoftplus(acc[mt][nt][3] + bb[3]));
      *(unsigned*)&x1s[bat * 520 + ch0] = pk;
    }
  }
  lds_barrier();

  // ---- stage 2: x2 = sp(x1 @ lin2^T + b4) ; A=W4, B=x1, D=x2^T ----
  f32x4 a2[4][4];
  #pragma unroll
  for (int mt = 0; mt < 4; ++mt)
    #pragma unroll
    for (int nt = 0; nt < 4; ++nt) a2[mt][nt] = (f32x4){0,0,0,0};
  for (int kc = 0; kc < 16; ++kc){
    long bf[4];
    #pragma unroll
    for (int nt = 0; nt < 4; ++nt)
      bf[nt] = *(const long*)&x1s[(nt * 16 + lrow) * 520 + kc * 32 + lq * 8];
    #pragma unroll
    for (int mt = 0; mt < 4; ++mt){
      long af = W4[((w * 4 + mt) * 16 + kc) * 64 + L];
      #pragma unroll
      for (int nt = 0; nt < 4; ++nt)
        a2[mt][nt] = mfma16f8(af, bf[nt], a2[mt][nt]);
    }
  }
  #pragma unroll
  for (int mt = 0; mt < 4; ++mt){
    const int ch0 = (w * 4 + mt) * 16 + lq * 4;
    f32x4 bb = *(const f32x4*)&b4[ch0];
    #pragma unroll
    for (int nt = 0; nt < 4; ++nt){
      const int bat = nt * 16 + lrow;
      unsigned pk = pk4fp8(fsoftplus(a2[mt][nt][0] + bb[0]),
                           fsoftplus(a2[mt][nt][1] + bb[1]),
                           fsoftplus(a2[mt][nt][2] + bb[2]),
                           fsoftplus(a2[mt][nt][3] + bb[3]));
      *(unsigned*)&x2s[bat * 264 + ch0] = pk;
    }
  }
  lds_barrier();

  // ---- stage 3: logits = sp(x2 @ tag^T + b5) ; normal roles ----
  f32x4 a3 = (f32x4){0,0,0,0};
  #pragma unroll
  for (int kc = 0; kc < 8; ++kc){
    long af = *(const long*)&x2s[(w * 16 + lrow) * 264 + kc * 32 + lq * 8];
    long bf = W5[kc * 64 + L];
    a3 = mfma16f8(af, bf, a3);
  }
  if (lrow < 12){
    float bb = b5[lrow];
    #pragma unroll
    for (int r = 0; r < 4; ++r)
      logits[(long)(m0 + w * 16 + lq * 4 + r) * 12 + lrow] = fsoftplus(a3[r] + bb);
  }
}

// ---------- CRF NLL: one wave per batch row; shfl alpha exchange ----------
// Zero barriers in the 200-step recursion: lane j holds alpha_j, cross-lane
// gather via __shfl (in-wave). sl staged once (read-only after 1 barrier).
__global__ void k_crf(const float* __restrict__ logits, const int* __restrict__ tags,
                      const int* __restrict__ lens, const float* __restrict__ trans,
                      float* __restrict__ nll)
{
  const int b = blockIdx.x;
  const int lane = threadIdx.x;            // 64
  __shared__ float sl[2400];               // [t][12]
  for (int e = lane; e < 2400; e += 64) sl[e] = logits[(long)b * 2400 + e];
  const int lj = (lane < 12) ? lane : 0;   // lanes >=12 mirror lane 0 (harmless)
  float tcol[12];
  #pragma unroll
  for (int i = 0; i < 12; ++i) tcol[i] = trans[i * 12 + lj];
  const int len = lens[b];
  float alpha = 0.0f;
  __syncthreads();

  for (int t = 0; t < len; ++t){
    float av[12];
    #pragma unroll
    for (int i = 0; i < 12; ++i)
      av[i] = __shfl(alpha, i, 64) + tcol[i];
    float mx = av[0];
    #pragma unroll
    for (int i = 1; i < 12; ++i) mx = fmaxf(mx, av[i]);
    float ss = 0.0f;
    #pragma unroll
    for (int i = 0; i < 12; ++i)
      ss += __builtin_amdgcn_exp2f(1.4426950408889634f * (av[i] - mx));
    alpha = sl[t * 12 + lj] + mx + 0.69314718055994531f * __builtin_amdgcn_logf(ss);
  }

  // total = logsumexp_j(alpha_j + trans[j][STOP])
  float tv = alpha + trans[lj * 12 + 11];
  float tmax = tv;
  #pragma unroll
  for (int i = 0; i < 12; ++i) tmax = fmaxf(tmax, __shfl(tv, i, 64));
  float tss = 0.0f;
  #pragma unroll
  for (int i = 0; i < 12; ++i)
    tss += __builtin_amdgcn_exp2f(1.4426950408889634f * (__shfl(tv, i, 64) - tmax));

  // real path score
  float rs = 0.0f;
  for (int t = lane; t < len; t += 64){
    int tg = tags[b * 200 + t];
    int pv = (t == 0) ? 10 : tags[b * 200 + t - 1];                 // START=10
    rs += sl[t * 12 + tg] + trans[pv * 12 + tg];
  }
  #pragma unroll
  for (int off = 32; off > 0; off >>= 1) rs += __shfl_down(rs, off, 64);
  if (lane == 0){
    float total = tmax + 0.69314718055994531f * __builtin_amdgcn_logf(tss);
    rs += trans[tags[b * 200 + len - 1] * 12 + 11];
    nll[b] = total - rs;
  }
}

__global__ void k_sum(const float* __restrict__ nll, float* __restrict__ out){
  __shared__ float red[256];
  int t = threadIdx.x;
  red[t] = nll[t];
  __syncthreads();
  for (int s = 128; s > 0; s >>= 1){
    if (t < s) red[t] += red[t + s];
    __syncthreads();
  }
  if (t == 0) out[0] = red[0];
}

// ---------- launcher ----------
extern "C" void kernel_launch(void* const* d_in, const int* in_sizes, int n_in,
                              void* d_out, int out_size, void* d_ws, size_t ws_size,
                              hipStream_t stream)
{
  (void)in_sizes; (void)n_in; (void)out_size; (void)ws_size;
  const int*   characters = (const int*)  d_in[0];
  const float* words      = (const float*)d_in[1];
  const int*   tags       = (const int*)  d_in[2];
  const int*   len_char   = (const int*)  d_in[3];
  const int*   len_word   = (const int*)  d_in[4];
  const float* char_emb   = (const float*)d_in[5];
  const float* char_Wih_f = (const float*)d_in[6];
  const float* char_Whh_f = (const float*)d_in[7];
  const float* char_b_f   = (const float*)d_in[8];
  const float* char_Wih_b = (const float*)d_in[9];
  const float* char_Whh_b = (const float*)d_in[10];
  const float* char_b_b   = (const float*)d_in[11];
  const float* char_lin_W = (const float*)d_in[12];
  const float* char_lin_b = (const float*)d_in[13];
  const float* word_Wih_f = (const float*)d_in[14];
  const float* word_Whh_f = (const float*)d_in[15];
  const float* word_b_f   = (const float*)d_in[16];
  const float* word_Wih_b = (const float*)d_in[17];
  const float* word_Whh_b = (const float*)d_in[18];
  const float* word_b_b   = (const float*)d_in[19];
  const float* word_lin_W = (const float*)d_in[20];
  const float* word_lin_b = (const float*)d_in[21];
  const float* lin1_W     = (const float*)d_in[22];
  const float* lin1_b     = (const float*)d_in[23];
  const float* lin2_W     = (const float*)d_in[24];
  const float* lin2_b     = (const float*)d_in[25];
  const float* tag_W      = (const float*)d_in[26];
  const float* tag_b      = (const float*)d_in[27];
  const float* trans      = (const float*)d_in[28];

  char* ws = (char*)d_ws;
  size_t off = 0;
  auto take = [&](size_t bytes) -> char* {
    char* p = ws + off;
    off = (off + bytes + 511) & ~(size_t)511;
    return p;
  };
  u8*   wsw_cf   = (u8*)take((size_t)262144);      // [w16][gt4][kc8][64x8B]
  u8*   wsw_cb   = (u8*)take((size_t)262144);
  u8*   wsw_wf   = (u8*)take((size_t)262144);
  u8*   wsw_wb   = (u8*)take((size_t)262144);
  u8*   ctab     = (u8*)take((size_t)262144);      // [dir2][v128][gcol256][gt4]
  u8*   wswgin_f = (u8*)take((size_t)64*4*512);
  u8*   wswgin_b = (u8*)take((size_t)64*4*512);
  u8*   wswg1    = (u8*)take((size_t)32*16*512);   // B-frag (char_lin)
  u8*   wswg2    = (u8*)take((size_t)16*16*512);   // B-frag (word_lin)
  u8*   wswg3    = (u8*)take((size_t)32*24*512);   // A-frag (lin1)
  u8*   wswg4    = (u8*)take((size_t)16*16*512);   // A-frag (lin2)
  u8*   wswg5    = (u8*)take((size_t)1*8*512);     // B-frag (tag)
  float* logits  = (float*)take((size_t)51200*12*4);
  float* nll     = (float*)take((size_t)256*4);
  u8*   h_char   = (u8*)take((size_t)51200*512);   // 25 MB fp8 (identity cols)
  u8*   h_word   = (u8*)take((size_t)51200*512);   // 25 MB fp8
  u8*   gin      = (u8*)take((size_t)105*1024*1024);  // reused post-lstm
  u8*   x_cat    = gin;                            // 51200*768 = 38.4 MB

  // preprocessing: ONE launch for all weight prep
  k_pre<<<8976, 256, 0, stream>>>(
      char_Whh_f, wsw_cf, char_Whh_b, wsw_cb, word_Whh_f, wsw_wf, word_Whh_b, wsw_wb,
      char_emb, char_Wih_f, char_b_f, char_Wih_b, char_b_b, ctab,
      word_Wih_f, word_Wih_b, wswgin_f, wswgin_b,
      char_lin_W, wswg1, word_lin_W, wswg2, tag_W, wswg5,
      lin1_W, wswg3, lin2_W, wswg4);

  // gin precompute (word input projection, f32 source), 4-row-page layout
  k_gin<<<1600, 512, 0, stream>>>(words, wswgin_f, wswgin_b, word_b_f, word_b_b, gin);

  // recurrences: 256 blocks x 1024 threads (4 batch rows per block)
  k_lstm<<<256, 1024, 0, stream>>>(characters, gin, ctab,
                                   wsw_cf, wsw_cb, wsw_wf, wsw_wb,
                                   len_char, len_word, h_char, h_word);

  // feed-forward: G1+G2 (R5 chunked), then fused G3+G4+G5 (R5 chunked)
  k_g12<<<dim3(400, 6), 256, 0, stream>>>(h_char, h_word, wswg1, wswg2,
                                          char_lin_b, word_lin_b, x_cat);
  k_tail<<<800, 256, 0, stream>>>(x_cat, wswg3, wswg4, wswg5,
                                  lin1_b, lin2_b, tag_b, logits);

  // CRF
  k_crf<<<256, 64, 0, stream>>>(logits, tags, len_char, trans, nll);
  k_sum<<<1, 256, 0, stream>>>(nll, (float*)d_out);
}